// Round 15
// baseline (586.360 us; speedup 1.0000x reference)
//
#include <hip/hip_runtime.h>

#define HID 128

// binned CSR build params
#define NB 256
#define BW 400
#define DEPTH 24
#define CH 2048

typedef __attribute__((ext_vector_type(8))) short bf16x8;
typedef __attribute__((ext_vector_type(4))) float f32x4;

// ---------------- bf16 helpers (RNE pack, shift unpack) ----------------
__device__ inline float blo(unsigned u) { return __uint_as_float(u << 16); }
__device__ inline float bhi(unsigned u) { return __uint_as_float(u & 0xffff0000u); }
__device__ inline unsigned rne16(float x) {
  unsigned u = __float_as_uint(x);
  return (u + 0x7fffu + ((u >> 16) & 1u)) >> 16;
}
__device__ inline unsigned pk2(float a, float b) { return (rne16(b) << 16) | rne16(a); }

// ---------------- fused: weight transpose/pack + state init ----------------
__device__ inline void prep_one(const float* __restrict__ W, unsigned* __restrict__ Wt,
                                int K, int KP2, int b) {
  int idx = b * 256 + threadIdx.x;
  if (idx >= 128 * KP2) return;
  int c = idx / KP2, kk = idx - c * KP2;
  int k0 = kk * 2, k1 = k0 + 1;
  float v0 = (k0 < K) ? W[(long)k0 * 128 + c] : 0.f;
  float v1 = (k1 < K) ? W[(long)k1 * 128 + c] : 0.f;
  Wt[idx] = pk2(v0, v1);
}

__global__ void k_prep_init(const float* __restrict__ w1, const float* __restrict__ w2,
                            const float* __restrict__ w3, unsigned* __restrict__ Wt1,
                            unsigned* __restrict__ Wt2, unsigned* __restrict__ Wt3,
                            float* __restrict__ psum, int* __restrict__ gstart,
                            int* __restrict__ bhist, int IN, int G) {
  int b = blockIdx.x;
  if (b < 72) prep_one(w1, Wt1, IN, 144, b);
  else if (b < 104) prep_one(w2, Wt2, 128, 64, b - 72);
  else prep_one(w3, Wt3, 128, 64, b - 104);
  if (b < 32) {
    int i = b * 256 + threadIdx.x;
    if (i < G * HID) psum[i] = 0.f;
    if (i <= G) gstart[i] = -1;
    if (i < NB) bhist[i] = 0;
  }
}

// ---------------- X f32 -> bf16 packed [N][132]u32 (k 260..263 zero) -------------
__global__ __launch_bounds__(256) void k_conv(const float* __restrict__ X,
                                              unsigned* __restrict__ Xb, int N) {
  long total = (long)N * 33;
  long stride = (long)gridDim.x * blockDim.x;
  for (long idx = (long)blockIdx.x * blockDim.x + threadIdx.x; idx < total; idx += stride) {
    long row = idx / 33;
    int q = (int)(idx - row * 33);
    uint4 o;
    if (q < 32) {
      const float* p = &X[row * 260 + q * 8];
      float4 u = *(const float4*)p, v = *(const float4*)(p + 4);
      o.x = pk2(u.x, u.y); o.y = pk2(u.z, u.w);
      o.z = pk2(v.x, v.y); o.w = pk2(v.z, v.w);
    } else {  // q == 32: floats 256..259 + zero pad
      const float* p = &X[row * 260 + 256];
      float4 u = *(const float4*)p;
      o.x = pk2(u.x, u.y); o.y = pk2(u.z, u.w);
      o.z = 0u; o.w = 0u;
    }
    *(uint4*)&Xb[row * 132 + q * 4] = o;
  }
}

// ---------------- bucket histogram (LDS-staged, int4 reads) ----------------
__global__ __launch_bounds__(256) void k_hist(const int* __restrict__ dst, int E, int N,
                                              int* __restrict__ bhist) {
  __shared__ int h[NB];
  int t = threadIdx.x;
  h[t] = 0;
  __syncthreads();
  int E4 = E >> 2;
  const int4* d4 = (const int4*)dst;
  int i = blockIdx.x * blockDim.x + t;
  int stride = gridDim.x * blockDim.x;
  for (; i < E4; i += stride) {
    int4 v = d4[i];
    atomicAdd(&h[(int)(((long long)v.x * NB) / N)], 1);
    atomicAdd(&h[(int)(((long long)v.y * NB) / N)], 1);
    atomicAdd(&h[(int)(((long long)v.z * NB) / N)], 1);
    atomicAdd(&h[(int)(((long long)v.w * NB) / N)], 1);
  }
  if (blockIdx.x == 0) {
    for (int e = E4 * 4 + t; e < E; e += 256)
      atomicAdd(&h[(int)(((long long)dst[e] * NB) / N)], 1);
  }
  __syncthreads();
  if (h[t]) atomicAdd(&bhist[t], h[t]);
}

// ---------------- parallel exclusive scan of bhist -> bstart, gcur ----------------
__global__ __launch_bounds__(NB) void k_bscan(const int* __restrict__ bhist,
                                              int* __restrict__ bstart,
                                              int* __restrict__ gcur, int E) {
  __shared__ int sh[NB];
  int t = threadIdx.x;
  int v = bhist[t];
  sh[t] = v;
  __syncthreads();
  for (int off = 1; off < NB; off <<= 1) {
    int x = (t >= off) ? sh[t - off] : 0;
    __syncthreads();
    sh[t] += x;
    __syncthreads();
  }
  int excl = sh[t] - v;
  bstart[t] = excl;
  gcur[t] = excl;
  if (t == NB - 1) bstart[NB] = sh[t];  // == E
}

// ---------------- LDS-staged scatter into bucket-major order (u32 packed) --------
// pack = (d_local << 17) | src. Each thread takes 8 consecutive edges (int4 x2).
__global__ __launch_bounds__(256) void k_scatter(const int* __restrict__ src,
                                                 const int* __restrict__ dst,
                                                 int E, int N,
                                                 unsigned* __restrict__ binned,
                                                 int* __restrict__ gcur) {
  __shared__ unsigned buf[NB][DEPTH]; // 24 KB
  __shared__ int cnt[NB];
  int t = threadIdx.x;
  long cover = (long)gridDim.x * CH;
  int nround = (int)((E + cover - 1) / cover);
  for (int r = 0; r < nround; ++r) {
    cnt[t] = 0;
    __syncthreads();
    long e0 = (long)r * cover + (long)blockIdx.x * CH + (long)t * 8;
    int svals[8], dvals[8];
    int cntv = 0;
    if (e0 + 8 <= E) {
      int4 s0 = *(const int4*)&src[e0], s1 = *(const int4*)&src[e0 + 4];
      int4 d0 = *(const int4*)&dst[e0], d1 = *(const int4*)&dst[e0 + 4];
      svals[0]=s0.x; svals[1]=s0.y; svals[2]=s0.z; svals[3]=s0.w;
      svals[4]=s1.x; svals[5]=s1.y; svals[6]=s1.z; svals[7]=s1.w;
      dvals[0]=d0.x; dvals[1]=d0.y; dvals[2]=d0.z; dvals[3]=d0.w;
      dvals[4]=d1.x; dvals[5]=d1.y; dvals[6]=d1.z; dvals[7]=d1.w;
      cntv = 8;
    } else {
      for (long e = e0; e < E; ++e) { svals[cntv]=src[e]; dvals[cntv]=dst[e]; ++cntv; }
    }
    for (int k = 0; k < cntv; ++k) {
      int s = svals[k], d = dvals[k];
      int b = (int)(((long long)d * NB) / N);
      int d0b = (int)(((long long)b * N + NB - 1) / NB);
      unsigned pack = ((unsigned)(d - d0b) << 17) | (unsigned)s;
      int slot = atomicAdd(&cnt[b], 1);
      if (slot < DEPTH) buf[b][slot] = pack;
      else { int g = atomicAdd(&gcur[b], 1); binned[g] = pack; } // rare spill
    }
    __syncthreads();
    {
      int c = cnt[t];
      if (c > DEPTH) c = DEPTH;
      if (c > 0) {
        int g = atomicAdd(&gcur[t], c);
        for (int k = 0; k < c; ++k) binned[g + k] = buf[t][k];
      }
    }
    __syncthreads();
  }
}

// ---------------- fused per-bucket: deg hist + local scan + place + rowstart -----
__global__ __launch_bounds__(256) void k_build(const unsigned* __restrict__ binned,
                                               const int* __restrict__ bstart, int N,
                                               int* __restrict__ deg,
                                               float* __restrict__ dinv,
                                               int* __restrict__ rowstart,
                                               int* __restrict__ csr) {
  __shared__ int hist[BW];
  __shared__ int loc[BW];
  __shared__ int scanbuf[256];
  int b = blockIdx.x;
  int t = threadIdx.x;
  int d0 = (int)(((long long)b * N + NB - 1) / NB);
  int d1 = (int)(((long long)(b + 1) * N + NB - 1) / NB);
  if (d1 > N) d1 = N;
  int W = d1 - d0;
  for (int w = t; w < BW; w += 256) hist[w] = 0;
  __syncthreads();
  int s = bstart[b], e = bstart[b + 1];
  for (int i = s + t; i < e; i += 256)
    atomicAdd(&hist[binned[i] >> 17], 1);
  __syncthreads();
  int e0 = t * 2, e1 = t * 2 + 1;
  int h0 = (e0 < W) ? hist[e0] : 0;
  int h1 = (e1 < W) ? hist[e1] : 0;
  scanbuf[t] = h0 + h1;
  __syncthreads();
  for (int off = 1; off < 256; off <<= 1) {
    int x = (t >= off) ? scanbuf[t - off] : 0;
    __syncthreads();
    scanbuf[t] += x;
    __syncthreads();
  }
  int excl = scanbuf[t] - (h0 + h1);
  if (e0 < W) loc[e0] = excl;
  if (e1 < W) loc[e1] = excl + h0;
  if (e0 < W) {
    deg[d0 + e0] = h0;
    dinv[d0 + e0] = rsqrtf((float)(h0 + 1));
    rowstart[d0 + e0] = s + loc[e0];
    hist[e0] = 0;
  }
  if (e1 < W) {
    deg[d0 + e1] = h1;
    dinv[d0 + e1] = rsqrtf((float)(h1 + 1));
    rowstart[d0 + e1] = s + loc[e1];
    hist[e1] = 0;
  }
  __syncthreads();
  for (int i = s + t; i < e; i += 256) {
    unsigned p = binned[i];
    int dl = (int)(p >> 17);
    int sn = (int)(p & 0x1ffffu);
    int pos = s + loc[dl] + atomicAdd(&hist[dl], 1);
    csr[pos] = sn;
  }
}

// ============ MFMA GEMM, layers 2/3: Cbf16 = dinv(row)*(Abf16[N][128] @ W[128][128]) ==
__global__ __launch_bounds__(256) void k_gemm_mf(const unsigned* __restrict__ A,
                                                 const unsigned* __restrict__ Wt,
                                                 const float* __restrict__ dscale,
                                                 unsigned* __restrict__ Cu, int N) {
  int t = threadIdx.x;
  int w = t >> 6;
  int l = t & 63;
  int lr = l & 15;
  int kg = l >> 4;
  int wr0 = blockIdx.x * 128 + w * 32;

  f32x4 acc[2][8];
#pragma unroll
  for (int rt = 0; rt < 2; ++rt)
#pragma unroll
    for (int f = 0; f < 8; ++f) acc[rt][f] = (f32x4){0.f, 0.f, 0.f, 0.f};

  int r0 = wr0 + lr, r1 = wr0 + 16 + lr;
#pragma unroll
  for (int kt = 0; kt < 4; ++kt) {
    int ko = kt * 16 + kg * 4;
    bf16x8 a0 = {}, a1 = {};
    if (r0 < N) a0 = *(const bf16x8*)&A[(long)r0 * 64 + ko];
    if (r1 < N) a1 = *(const bf16x8*)&A[(long)r1 * 64 + ko];
#pragma unroll
    for (int f = 0; f < 8; ++f) {
      bf16x8 b = *(const bf16x8*)&Wt[(f * 16 + lr) * 64 + ko];
      acc[0][f] = __builtin_amdgcn_mfma_f32_16x16x32_bf16(a0, b, acc[0][f], 0, 0, 0);
      acc[1][f] = __builtin_amdgcn_mfma_f32_16x16x32_bf16(a1, b, acc[1][f], 0, 0, 0);
    }
  }
#pragma unroll
  for (int rt = 0; rt < 2; ++rt) {
#pragma unroll
    for (int reg = 0; reg < 4; ++reg) {
      int row = wr0 + rt * 16 + kg * 4 + reg;
      float ds = (row < N) ? dscale[row] : 0.f;
#pragma unroll
      for (int f = 0; f < 8; ++f) {
        float v = acc[rt][f][reg] * ds;
        float pv = __shfl_xor(v, 1);
        if (!(l & 1) && row < N)
          Cu[(long)row * 64 + ((f * 16 + lr) >> 1)] = pk2(v, pv);
      }
    }
  }
}

// ============ MFMA GEMM, layer 1 from pre-packed Xb [N][132]u32, K=288-pad ============
__global__ __launch_bounds__(256) void k_gemm1b(const unsigned* __restrict__ A,
                                                const unsigned* __restrict__ Wt,
                                                const float* __restrict__ dscale,
                                                unsigned* __restrict__ Cu, int N) {
  int t = threadIdx.x;
  int w = t >> 6;
  int l = t & 63;
  int lr = l & 15;
  int kg = l >> 4;
  int wr0 = blockIdx.x * 128 + w * 32;

  f32x4 acc[2][8];
#pragma unroll
  for (int rt = 0; rt < 2; ++rt)
#pragma unroll
    for (int f = 0; f < 8; ++f) acc[rt][f] = (f32x4){0.f, 0.f, 0.f, 0.f};

  int r0 = wr0 + lr, r1 = wr0 + 16 + lr;
#pragma unroll
  for (int kt = 0; kt < 8; ++kt) {
    int ko = kt * 16 + kg * 4;
    bf16x8 a0 = {}, a1 = {};
    if (r0 < N) a0 = *(const bf16x8*)&A[(long)r0 * 132 + ko];
    if (r1 < N) a1 = *(const bf16x8*)&A[(long)r1 * 132 + ko];
#pragma unroll
    for (int f = 0; f < 8; ++f) {
      bf16x8 b = *(const bf16x8*)&Wt[(f * 16 + lr) * 144 + ko];
      acc[0][f] = __builtin_amdgcn_mfma_f32_16x16x32_bf16(a0, b, acc[0][f], 0, 0, 0);
      acc[1][f] = __builtin_amdgcn_mfma_f32_16x16x32_bf16(a1, b, acc[1][f], 0, 0, 0);
    }
  }
  // tail: k 256..287; only kg==0 has data (u32 128..131, zero-padded past 260)
  {
    int ko = 128 + kg * 4;
    bf16x8 a0 = {}, a1 = {};
    if (kg == 0) {
      if (r0 < N) a0 = *(const bf16x8*)&A[(long)r0 * 132 + 128];
      if (r1 < N) a1 = *(const bf16x8*)&A[(long)r1 * 132 + 128];
    }
#pragma unroll
    for (int f = 0; f < 8; ++f) {
      bf16x8 b = *(const bf16x8*)&Wt[(f * 16 + lr) * 144 + ko];
      acc[0][f] = __builtin_amdgcn_mfma_f32_16x16x32_bf16(a0, b, acc[0][f], 0, 0, 0);
      acc[1][f] = __builtin_amdgcn_mfma_f32_16x16x32_bf16(a1, b, acc[1][f], 0, 0, 0);
    }
  }
#pragma unroll
  for (int rt = 0; rt < 2; ++rt) {
#pragma unroll
    for (int reg = 0; reg < 4; ++reg) {
      int row = wr0 + rt * 16 + kg * 4 + reg;
      float ds = (row < N) ? dscale[row] : 0.f;
#pragma unroll
      for (int f = 0; f < 8; ++f) {
        float v = acc[rt][f][reg] * ds;
        float pv = __shfl_xor(v, 1);
        if (!(l & 1) && row < N)
          Cu[(long)row * 64 + ((f * 16 + lr) >> 1)] = pk2(v, pv);
      }
    }
  }
}

// ============ MFMA GEMM, layer 1 fallback: x f32 -> bf16 in-flight ============
__global__ __launch_bounds__(256) void k_gemm1_mf(const float* __restrict__ X,
                                                  const unsigned* __restrict__ Wt,
                                                  const float* __restrict__ dscale,
                                                  unsigned* __restrict__ Cu, int N, int K) {
  int t = threadIdx.x;
  int w = t >> 6;
  int l = t & 63;
  int lr = l & 15;
  int kg = l >> 4;
  int wr0 = blockIdx.x * 128 + w * 32;

  f32x4 acc[2][8];
#pragma unroll
  for (int rt = 0; rt < 2; ++rt)
#pragma unroll
    for (int f = 0; f < 8; ++f) acc[rt][f] = (f32x4){0.f, 0.f, 0.f, 0.f};

  int r0 = wr0 + lr, r1 = wr0 + 16 + lr;
  int nkt = (K + 31) / 32;  // 9 for K=260
  for (int kt = 0; kt < nkt; ++kt) {
    int kb = kt * 32 + kg * 8;
    bf16x8 a0 = {}, a1 = {};
    if (kb + 7 < K) {
      if (r0 < N) {
        const float* p = &X[(long)r0 * K + kb];
        float4 u = *(const float4*)p, v = *(const float4*)(p + 4);
        union { uint4 q; bf16x8 b; } cv;
        cv.q.x = pk2(u.x, u.y); cv.q.y = pk2(u.z, u.w);
        cv.q.z = pk2(v.x, v.y); cv.q.w = pk2(v.z, v.w);
        a0 = cv.b;
      }
      if (r1 < N) {
        const float* p = &X[(long)r1 * K + kb];
        float4 u = *(const float4*)p, v = *(const float4*)(p + 4);
        union { uint4 q; bf16x8 b; } cv;
        cv.q.x = pk2(u.x, u.y); cv.q.y = pk2(u.z, u.w);
        cv.q.z = pk2(v.x, v.y); cv.q.w = pk2(v.z, v.w);
        a1 = cv.b;
      }
    } else if (kb < K) {  // partial tail (k=256..259)
      float t0[8], t1[8];
#pragma unroll
      for (int j = 0; j < 8; ++j) {
        int k = kb + j;
        t0[j] = (r0 < N && k < K) ? X[(long)r0 * K + k] : 0.f;
        t1[j] = (r1 < N && k < K) ? X[(long)r1 * K + k] : 0.f;
      }
      union { uint4 q; bf16x8 b; } c0, c1;
      c0.q.x = pk2(t0[0], t0[1]); c0.q.y = pk2(t0[2], t0[3]);
      c0.q.z = pk2(t0[4], t0[5]); c0.q.w = pk2(t0[6], t0[7]);
      c1.q.x = pk2(t1[0], t1[1]); c1.q.y = pk2(t1[2], t1[3]);
      c1.q.z = pk2(t1[4], t1[5]); c1.q.w = pk2(t1[6], t1[7]);
      a0 = c0.b; a1 = c1.b;
    }
    int ko = kt * 16 + kg * 4;
#pragma unroll
    for (int f = 0; f < 8; ++f) {
      bf16x8 b = *(const bf16x8*)&Wt[(f * 16 + lr) * 144 + ko];
      acc[0][f] = __builtin_amdgcn_mfma_f32_16x16x32_bf16(a0, b, acc[0][f], 0, 0, 0);
      acc[1][f] = __builtin_amdgcn_mfma_f32_16x16x32_bf16(a1, b, acc[1][f], 0, 0, 0);
    }
  }
#pragma unroll
  for (int rt = 0; rt < 2; ++rt) {
#pragma unroll
    for (int reg = 0; reg < 4; ++reg) {
      int row = wr0 + rt * 16 + kg * 4 + reg;
      float ds = (row < N) ? dscale[row] : 0.f;
#pragma unroll
      for (int f = 0; f < 8; ++f) {
        float v = acc[rt][f][reg] * ds;
        float pv = __shfl_xor(v, 1);
        if (!(l & 1) && row < N)
          Cu[(long)row * 64 + ((f * 16 + lr) >> 1)] = pk2(v, pv);
      }
    }
  }
}

// ---------------- pull aggregation v4: 16 lanes x uint4 per node ----------------
__global__ __launch_bounds__(256) void k_agg(const uint4* __restrict__ T4,  // [N][16]
                                             const float* __restrict__ dinv,
                                             const int* __restrict__ rowstart,
                                             const int* __restrict__ deg,
                                             const int* __restrict__ csr,
                                             const float* __restrict__ bias,
                                             uint4* __restrict__ outu,      // [N][16]
                                             int N) {
  int t = threadIdx.x;
  int grp = t >> 4;        // node slot 0..15
  int lane = t & 15;       // uint4 slot in row (8 channels)
  int i = blockIdx.x * 16 + grp;
  if (i >= N) return;

  int c0 = lane * 8;
  float b0 = bias[c0 + 0], b1 = bias[c0 + 1], b2 = bias[c0 + 2], b3 = bias[c0 + 3];
  float b4 = bias[c0 + 4], b5 = bias[c0 + 5], b6 = bias[c0 + 6], b7 = bias[c0 + 7];

  uint4 su = T4[(long)i * 16 + lane];  // self-loop (pre-scaled)
  float a0 = blo(su.x), a1 = bhi(su.x), a2 = blo(su.y), a3 = bhi(su.y);
  float a4 = blo(su.z), a5 = bhi(su.z), a6 = blo(su.w), a7 = bhi(su.w);

  int s0 = rowstart[i];
  int d = deg[i];
  int j = 0;
  for (; j + 3 < d; j += 4) {
    int n1 = csr[s0 + j];
    int n2 = csr[s0 + j + 1];
    int n3 = csr[s0 + j + 2];
    int n4 = csr[s0 + j + 3];
    uint4 u1 = T4[(long)n1 * 16 + lane];
    uint4 u2 = T4[(long)n2 * 16 + lane];
    uint4 u3 = T4[(long)n3 * 16 + lane];
    uint4 u4 = T4[(long)n4 * 16 + lane];
    a0 += (blo(u1.x) + blo(u2.x)) + (blo(u3.x) + blo(u4.x));
    a1 += (bhi(u1.x) + bhi(u2.x)) + (bhi(u3.x) + bhi(u4.x));
    a2 += (blo(u1.y) + blo(u2.y)) + (blo(u3.y) + blo(u4.y));
    a3 += (bhi(u1.y) + bhi(u2.y)) + (bhi(u3.y) + bhi(u4.y));
    a4 += (blo(u1.z) + blo(u2.z)) + (blo(u3.z) + blo(u4.z));
    a5 += (bhi(u1.z) + bhi(u2.z)) + (bhi(u3.z) + bhi(u4.z));
    a6 += (blo(u1.w) + blo(u2.w)) + (blo(u3.w) + blo(u4.w));
    a7 += (bhi(u1.w) + bhi(u2.w)) + (bhi(u3.w) + bhi(u4.w));
  }
  for (; j < d; ++j) {
    int n1 = csr[s0 + j];
    uint4 u1 = T4[(long)n1 * 16 + lane];
    a0 += blo(u1.x); a1 += bhi(u1.x); a2 += blo(u1.y); a3 += bhi(u1.y);
    a4 += blo(u1.z); a5 += bhi(u1.z); a6 += blo(u1.w); a7 += bhi(u1.w);
  }
  float di = dinv[i];
  float v0 = fmaxf(di * a0 + b0, 0.f);
  float v1 = fmaxf(di * a1 + b1, 0.f);
  float v2 = fmaxf(di * a2 + b2, 0.f);
  float v3 = fmaxf(di * a3 + b3, 0.f);
  float v4 = fmaxf(di * a4 + b4, 0.f);
  float v5 = fmaxf(di * a5 + b5, 0.f);
  float v6 = fmaxf(di * a6 + b6, 0.f);
  float v7 = fmaxf(di * a7 + b7, 0.f);
  uint4 o;
  o.x = pk2(v0, v1); o.y = pk2(v2, v3); o.z = pk2(v4, v5); o.w = pk2(v6, v7);
  outu[(long)i * 16 + lane] = o;
}

// ---------------- graph start offsets from sorted batch ----------------
__global__ void k_starts(const int* __restrict__ batch, int N, int* __restrict__ start) {
  int i = blockIdx.x * blockDim.x + threadIdx.x;
  int stride = gridDim.x * blockDim.x;
  for (; i < N; i += stride) {
    int g = batch[i];
    if (i == 0) {
      start[g] = 0;
    } else if (batch[i - 1] != g) {
      start[g] = i;
    }
  }
}

// parallel back-fill of empty graphs via reverse min-scan (starts monotone)
__global__ __launch_bounds__(256) void k_fix_starts(int* __restrict__ start, int G, int N) {
  __shared__ int sh[256];
  int t = threadIdx.x;
  int v = (t < G) ? start[t] : N;
  if (v < 0) v = N;
  sh[t] = v;
  __syncthreads();
  for (int off = 1; off < 256; off <<= 1) {
    int x = (t + off < 256) ? sh[t + off] : N;
    int nv = min(sh[t], x);
    __syncthreads();
    sh[t] = nv;
    __syncthreads();
  }
  if (t < G) start[t] = sh[t];
  if (t == 0) start[G] = N;
}

// ---------------- parallel mean-pool (batch sorted, h bf16 [N][64]) -------------
__global__ __launch_bounds__(256) void k_pool2(const unsigned* __restrict__ hu,
                                               const int* __restrict__ batch,
                                               float* __restrict__ psum, int N) {
  int t = threadIdx.x;
  int rg = t >> 6;        // row group 0..3
  int lane = t & 63;      // u32 index in row
  long base = (long)blockIdx.x * 64;
  float a0 = 0.f, a1 = 0.f;
  int cur = -1;
#pragma unroll
  for (int j = 0; j < 16; ++j) {
    long r = base + j * 4 + rg;
    if (r >= N) break;
    int g = batch[r];
    if (g != cur) {
      if (cur >= 0) {
        atomicAdd(&psum[cur * HID + lane * 2], a0);
        atomicAdd(&psum[cur * HID + lane * 2 + 1], a1);
        a0 = 0.f; a1 = 0.f;
      }
      cur = g;
    }
    unsigned u = hu[r * 64 + lane];
    a0 += blo(u); a1 += bhi(u);
  }
  if (cur >= 0) {
    atomicAdd(&psum[cur * HID + lane * 2], a0);
    atomicAdd(&psum[cur * HID + lane * 2 + 1], a1);
  }
}

// ---------------- MLP head ----------------
__global__ __launch_bounds__(128) void k_head(const float* __restrict__ psum,
                                              const int* __restrict__ gstart,
                                              const float* __restrict__ fc1w,
                                              const float* __restrict__ fc1b,
                                              const float* __restrict__ fc2w,
                                              const float* __restrict__ fc2b,
                                              float* __restrict__ out, int G) {
  __shared__ float pooled[HID];
  __shared__ float z1[HID];
  int g = blockIdx.x;
  int c = threadIdx.x;
  float cn = fmaxf((float)(gstart[g + 1] - gstart[g]), 1.f);
  pooled[c] = psum[g * HID + c] / cn;
  __syncthreads();
  float a = fc1b[c];
#pragma unroll 8
  for (int k = 0; k < HID; ++k) a += pooled[k] * fc1w[k * HID + c];
  z1[c] = fmaxf(a, 0.f);
  __syncthreads();
  if (c < 16) {
    float o = fc2b[c];
#pragma unroll 8
    for (int k = 0; k < HID; ++k) o += z1[k] * fc2w[k * 16 + c];
    out[g * 16 + c] = o;
  }
}

extern "C" void kernel_launch(void* const* d_in, const int* in_sizes, int n_in,
                              void* d_out, int out_size, void* d_ws, size_t ws_size,
                              hipStream_t stream) {
  const float* x     = (const float*)d_in[0];
  const int*   ei    = (const int*)d_in[1];
  const int*   batch = (const int*)d_in[2];
  const float* w1    = (const float*)d_in[3];
  const float* b1    = (const float*)d_in[4];
  const float* w2    = (const float*)d_in[5];
  const float* b2    = (const float*)d_in[6];
  const float* w3    = (const float*)d_in[7];
  const float* b3    = (const float*)d_in[8];
  const float* fc1w  = (const float*)d_in[9];
  const float* fc1b  = (const float*)d_in[10];
  const float* fc2w  = (const float*)d_in[11];
  const float* fc2b  = (const float*)d_in[12];
  float* out = (float*)d_out;

  const int IN = in_sizes[3] / HID;   // 260
  const int N  = in_sizes[0] / IN;    // 100000
  const int E  = in_sizes[1] / 2;     // 3200000
  const int G  = out_size / 16;       // 64

  const int* srcp = ei;
  const int* dstp = ei + E;

  // ---- workspace carve ----
  char* wsp = (char*)d_ws;
  auto alloc = [&](size_t bytes) {
    char* p = wsp;
    wsp += (bytes + 255) & ~(size_t)255;
    return p;
  };
  int*   deg      = (int*)alloc((size_t)N * 4);
  int*   rowstart = (int*)alloc((size_t)N * 4);
  int*   bhist    = (int*)alloc(NB * 4);
  int*   bstart   = (int*)alloc((NB + 1) * 4);
  int*   gcur     = (int*)alloc(NB * 4);
  int*   gstart   = (int*)alloc((size_t)(G + 1) * 4);
  float* dinv     = (float*)alloc((size_t)N * 4);
  float* psum     = (float*)alloc((size_t)G * HID * 4);
  unsigned* Wt1   = (unsigned*)alloc(128 * 144 * 4);
  unsigned* Wt2   = (unsigned*)alloc(128 * 64 * 4);
  unsigned* Wt3   = (unsigned*)alloc(128 * 64 * 4);
  int*   csr      = (int*)alloc((size_t)E * 4);
  unsigned* bufA  = (unsigned*)alloc((size_t)N * 64 * 4);  // bf16 [N][128] packed
  unsigned* bufB  = (unsigned*)alloc((size_t)N * 64 * 4);  // bf16 [N][128] packed
  // binned edge array (E x 4B = 12.8MB) aliases bufA; consumed before first GEMM.
  unsigned* binned = (unsigned*)bufA;
  // optional pre-packed X (bf16, [N][132]u32 = 52.8MB) if workspace allows
  unsigned* Xb = (unsigned*)alloc((size_t)N * 132 * 4);
  bool fast1 = ((size_t)(wsp - (char*)d_ws) <= ws_size);

  // ---- fused prep (weights + init) ----
  k_prep_init<<<136, 256, 0, stream>>>(w1, w2, w3, Wt1, Wt2, Wt3,
                                       psum, gstart, bhist, IN, G);

  // ---- binned CSR build (u32-packed, fused build) ----
  k_hist<<<512, 256, 0, stream>>>(dstp, E, N, bhist);
  k_bscan<<<1, NB, 0, stream>>>(bhist, bstart, gcur, E);
  k_scatter<<<782, 256, 0, stream>>>(srcp, dstp, E, N, binned, gcur);
  k_build<<<NB, 256, 0, stream>>>(binned, bstart, N, deg, dinv, rowstart, csr);

  // ---- graph boundaries ----
  k_starts<<<256, 256, 0, stream>>>(batch, N, gstart);
  k_fix_starts<<<1, 256, 0, stream>>>(gstart, G, N);

  // ---- 3 GCN layers: MFMA GEMM (epilogue scales by dinv, packs bf16) + agg ----
  int gblocks = (N + 127) / 128;
  int ablocks = (N + 15) / 16;
  if (fast1) {
    k_conv<<<2048, 256, 0, stream>>>(x, Xb, N);
    k_gemm1b<<<gblocks, 256, 0, stream>>>(Xb, Wt1, dinv, bufA, N);
  } else {
    k_gemm1_mf<<<gblocks, 256, 0, stream>>>(x, Wt1, dinv, bufA, N, IN);
  }
  k_agg<<<ablocks, 256, 0, stream>>>((const uint4*)bufA, dinv, rowstart, deg, csr, b1,
                                     (uint4*)bufB, N);

  k_gemm_mf<<<gblocks, 256, 0, stream>>>(bufB, Wt2, dinv, bufA, N);
  k_agg<<<ablocks, 256, 0, stream>>>((const uint4*)bufA, dinv, rowstart, deg, csr, b2,
                                     (uint4*)bufB, N);

  k_gemm_mf<<<gblocks, 256, 0, stream>>>(bufB, Wt3, dinv, bufA, N);
  k_agg<<<ablocks, 256, 0, stream>>>((const uint4*)bufA, dinv, rowstart, deg, csr, b3,
                                     (uint4*)bufB, N);

  // ---- pool + head ----
  int pblocks = (N + 63) / 64;
  k_pool2<<<pblocks, 256, 0, stream>>>(bufB, batch, psum, N);
  k_head<<<G, 128, 0, stream>>>(psum, gstart, fc1w, fc1b, fc2w, fc2b, out, G);
}

// Round 16
// 576.323 us; speedup vs baseline: 1.0174x; 1.0174x over previous
//
#include <hip/hip_runtime.h>

#define HID 128

// binned CSR build params
#define NB 256
#define BW 400
#define DEPTH 24
#define CH 2048

typedef __attribute__((ext_vector_type(8))) short bf16x8;
typedef __attribute__((ext_vector_type(4))) float f32x4;

// ---------------- bf16 helpers (RNE pack, shift unpack) ----------------
__device__ inline float blo(unsigned u) { return __uint_as_float(u << 16); }
__device__ inline float bhi(unsigned u) { return __uint_as_float(u & 0xffff0000u); }
__device__ inline unsigned rne16(float x) {
  unsigned u = __float_as_uint(x);
  return (u + 0x7fffu + ((u >> 16) & 1u)) >> 16;
}
__device__ inline unsigned pk2(float a, float b) { return (rne16(b) << 16) | rne16(a); }

// ---------------- fused: weight transpose/pack + state init ----------------
__device__ inline void prep_one(const float* __restrict__ W, unsigned* __restrict__ Wt,
                                int K, int KP2, int b) {
  int idx = b * 256 + threadIdx.x;
  if (idx >= 128 * KP2) return;
  int c = idx / KP2, kk = idx - c * KP2;
  int k0 = kk * 2, k1 = k0 + 1;
  float v0 = (k0 < K) ? W[(long)k0 * 128 + c] : 0.f;
  float v1 = (k1 < K) ? W[(long)k1 * 128 + c] : 0.f;
  Wt[idx] = pk2(v0, v1);
}

__global__ void k_prep_init(const float* __restrict__ w1, const float* __restrict__ w2,
                            const float* __restrict__ w3, unsigned* __restrict__ Wt1,
                            unsigned* __restrict__ Wt2, unsigned* __restrict__ Wt3,
                            float* __restrict__ psum, int* __restrict__ gstart,
                            int* __restrict__ bhist, int IN, int G) {
  int b = blockIdx.x;
  if (b < 72) prep_one(w1, Wt1, IN, 144, b);
  else if (b < 104) prep_one(w2, Wt2, 128, 64, b - 72);
  else prep_one(w3, Wt3, 128, 64, b - 104);
  if (b < 32) {
    int i = b * 256 + threadIdx.x;
    if (i < G * HID) psum[i] = 0.f;
    if (i <= G) gstart[i] = -1;
    if (i < NB) bhist[i] = 0;
  }
}

// ---------------- bucket histogram (LDS-staged, int4 reads) ----------------
__global__ __launch_bounds__(256) void k_hist(const int* __restrict__ dst, int E, int N,
                                              int* __restrict__ bhist) {
  __shared__ int h[NB];
  int t = threadIdx.x;
  h[t] = 0;
  __syncthreads();
  int E4 = E >> 2;
  const int4* d4 = (const int4*)dst;
  int i = blockIdx.x * blockDim.x + t;
  int stride = gridDim.x * blockDim.x;
  for (; i < E4; i += stride) {
    int4 v = d4[i];
    atomicAdd(&h[(int)(((long long)v.x * NB) / N)], 1);
    atomicAdd(&h[(int)(((long long)v.y * NB) / N)], 1);
    atomicAdd(&h[(int)(((long long)v.z * NB) / N)], 1);
    atomicAdd(&h[(int)(((long long)v.w * NB) / N)], 1);
  }
  if (blockIdx.x == 0) {
    for (int e = E4 * 4 + t; e < E; e += 256)
      atomicAdd(&h[(int)(((long long)dst[e] * NB) / N)], 1);
  }
  __syncthreads();
  if (h[t]) atomicAdd(&bhist[t], h[t]);
}

// ---------------- parallel exclusive scan of bhist -> bstart, gcur ----------------
__global__ __launch_bounds__(NB) void k_bscan(const int* __restrict__ bhist,
                                              int* __restrict__ bstart,
                                              int* __restrict__ gcur, int E) {
  __shared__ int sh[NB];
  int t = threadIdx.x;
  int v = bhist[t];
  sh[t] = v;
  __syncthreads();
  for (int off = 1; off < NB; off <<= 1) {
    int x = (t >= off) ? sh[t - off] : 0;
    __syncthreads();
    sh[t] += x;
    __syncthreads();
  }
  int excl = sh[t] - v;
  bstart[t] = excl;
  gcur[t] = excl;
  if (t == NB - 1) bstart[NB] = sh[t];  // == E
}

// ---------------- LDS-staged scatter into bucket-major order (u32 packed) --------
// pack = (d_local << 17) | src. Each thread takes 8 consecutive edges (int4 x2).
__global__ __launch_bounds__(256) void k_scatter(const int* __restrict__ src,
                                                 const int* __restrict__ dst,
                                                 int E, int N,
                                                 unsigned* __restrict__ binned,
                                                 int* __restrict__ gcur) {
  __shared__ unsigned buf[NB][DEPTH]; // 24 KB
  __shared__ int cnt[NB];
  int t = threadIdx.x;
  long cover = (long)gridDim.x * CH;
  int nround = (int)((E + cover - 1) / cover);
  for (int r = 0; r < nround; ++r) {
    cnt[t] = 0;
    __syncthreads();
    long e0 = (long)r * cover + (long)blockIdx.x * CH + (long)t * 8;
    int svals[8], dvals[8];
    int cntv = 0;
    if (e0 + 8 <= E) {
      int4 s0 = *(const int4*)&src[e0], s1 = *(const int4*)&src[e0 + 4];
      int4 d0 = *(const int4*)&dst[e0], d1 = *(const int4*)&dst[e0 + 4];
      svals[0]=s0.x; svals[1]=s0.y; svals[2]=s0.z; svals[3]=s0.w;
      svals[4]=s1.x; svals[5]=s1.y; svals[6]=s1.z; svals[7]=s1.w;
      dvals[0]=d0.x; dvals[1]=d0.y; dvals[2]=d0.z; dvals[3]=d0.w;
      dvals[4]=d1.x; dvals[5]=d1.y; dvals[6]=d1.z; dvals[7]=d1.w;
      cntv = 8;
    } else {
      for (long e = e0; e < E; ++e) { svals[cntv]=src[e]; dvals[cntv]=dst[e]; ++cntv; }
    }
    for (int k = 0; k < cntv; ++k) {
      int s = svals[k], d = dvals[k];
      int b = (int)(((long long)d * NB) / N);
      int d0b = (int)(((long long)b * N + NB - 1) / NB);
      unsigned pack = ((unsigned)(d - d0b) << 17) | (unsigned)s;
      int slot = atomicAdd(&cnt[b], 1);
      if (slot < DEPTH) buf[b][slot] = pack;
      else { int g = atomicAdd(&gcur[b], 1); binned[g] = pack; } // rare spill
    }
    __syncthreads();
    {
      int c = cnt[t];
      if (c > DEPTH) c = DEPTH;
      if (c > 0) {
        int g = atomicAdd(&gcur[t], c);
        for (int k = 0; k < c; ++k) binned[g + k] = buf[t][k];
      }
    }
    __syncthreads();
  }
}

// ---------------- fused per-bucket: deg hist + local scan + place + rowstart -----
__global__ __launch_bounds__(256) void k_build(const unsigned* __restrict__ binned,
                                               const int* __restrict__ bstart, int N,
                                               int* __restrict__ deg,
                                               float* __restrict__ dinv,
                                               int* __restrict__ rowstart,
                                               int* __restrict__ csr) {
  __shared__ int hist[BW];
  __shared__ int loc[BW];
  __shared__ int scanbuf[256];
  int b = blockIdx.x;
  int t = threadIdx.x;
  int d0 = (int)(((long long)b * N + NB - 1) / NB);
  int d1 = (int)(((long long)(b + 1) * N + NB - 1) / NB);
  if (d1 > N) d1 = N;
  int W = d1 - d0;
  for (int w = t; w < BW; w += 256) hist[w] = 0;
  __syncthreads();
  int s = bstart[b], e = bstart[b + 1];
  for (int i = s + t; i < e; i += 256)
    atomicAdd(&hist[binned[i] >> 17], 1);
  __syncthreads();
  int e0 = t * 2, e1 = t * 2 + 1;
  int h0 = (e0 < W) ? hist[e0] : 0;
  int h1 = (e1 < W) ? hist[e1] : 0;
  scanbuf[t] = h0 + h1;
  __syncthreads();
  for (int off = 1; off < 256; off <<= 1) {
    int x = (t >= off) ? scanbuf[t - off] : 0;
    __syncthreads();
    scanbuf[t] += x;
    __syncthreads();
  }
  int excl = scanbuf[t] - (h0 + h1);
  if (e0 < W) loc[e0] = excl;
  if (e1 < W) loc[e1] = excl + h0;
  if (e0 < W) {
    deg[d0 + e0] = h0;
    dinv[d0 + e0] = rsqrtf((float)(h0 + 1));
    rowstart[d0 + e0] = s + loc[e0];
    hist[e0] = 0;
  }
  if (e1 < W) {
    deg[d0 + e1] = h1;
    dinv[d0 + e1] = rsqrtf((float)(h1 + 1));
    rowstart[d0 + e1] = s + loc[e1];
    hist[e1] = 0;
  }
  __syncthreads();
  for (int i = s + t; i < e; i += 256) {
    unsigned p = binned[i];
    int dl = (int)(p >> 17);
    int sn = (int)(p & 0x1ffffu);
    int pos = s + loc[dl] + atomicAdd(&hist[dl], 1);
    csr[pos] = sn;
  }
}

// ============ MFMA GEMM, layers 2/3: Cbf16 = dinv(row)*(Abf16[N][128] @ W[128][128]) ==
__global__ __launch_bounds__(256) void k_gemm_mf(const unsigned* __restrict__ A,
                                                 const unsigned* __restrict__ Wt,
                                                 const float* __restrict__ dscale,
                                                 unsigned* __restrict__ Cu, int N) {
  int t = threadIdx.x;
  int w = t >> 6;
  int l = t & 63;
  int lr = l & 15;
  int kg = l >> 4;
  int wr0 = blockIdx.x * 128 + w * 32;

  f32x4 acc[2][8];
#pragma unroll
  for (int rt = 0; rt < 2; ++rt)
#pragma unroll
    for (int f = 0; f < 8; ++f) acc[rt][f] = (f32x4){0.f, 0.f, 0.f, 0.f};

  int r0 = wr0 + lr, r1 = wr0 + 16 + lr;
#pragma unroll
  for (int kt = 0; kt < 4; ++kt) {
    int ko = kt * 16 + kg * 4;
    bf16x8 a0 = {}, a1 = {};
    if (r0 < N) a0 = *(const bf16x8*)&A[(long)r0 * 64 + ko];
    if (r1 < N) a1 = *(const bf16x8*)&A[(long)r1 * 64 + ko];
#pragma unroll
    for (int f = 0; f < 8; ++f) {
      bf16x8 b = *(const bf16x8*)&Wt[(f * 16 + lr) * 64 + ko];
      acc[0][f] = __builtin_amdgcn_mfma_f32_16x16x32_bf16(a0, b, acc[0][f], 0, 0, 0);
      acc[1][f] = __builtin_amdgcn_mfma_f32_16x16x32_bf16(a1, b, acc[1][f], 0, 0, 0);
    }
  }
#pragma unroll
  for (int rt = 0; rt < 2; ++rt) {
#pragma unroll
    for (int reg = 0; reg < 4; ++reg) {
      int row = wr0 + rt * 16 + kg * 4 + reg;
      float ds = (row < N) ? dscale[row] : 0.f;
#pragma unroll
      for (int f = 0; f < 8; ++f) {
        float v = acc[rt][f][reg] * ds;
        float pv = __shfl_xor(v, 1);
        if (!(l & 1) && row < N)
          Cu[(long)row * 64 + ((f * 16 + lr) >> 1)] = pk2(v, pv);
      }
    }
  }
}

// ============ MFMA GEMM, layer 1: x f32 -> bf16 in-flight, K=260 unrolled ============
// 8 fully-unrolled K-tiles (kb+7 <= 255 < 260 for kt<=7) + explicit kt=8 tail.
__global__ __launch_bounds__(256) void k_gemm1_mf(const float* __restrict__ X,
                                                  const unsigned* __restrict__ Wt,
                                                  const float* __restrict__ dscale,
                                                  unsigned* __restrict__ Cu, int N) {
  const int K = 260;
  int t = threadIdx.x;
  int w = t >> 6;
  int l = t & 63;
  int lr = l & 15;
  int kg = l >> 4;
  int wr0 = blockIdx.x * 128 + w * 32;

  f32x4 acc[2][8];
#pragma unroll
  for (int rt = 0; rt < 2; ++rt)
#pragma unroll
    for (int f = 0; f < 8; ++f) acc[rt][f] = (f32x4){0.f, 0.f, 0.f, 0.f};

  int r0 = wr0 + lr, r1 = wr0 + 16 + lr;
  bool v0ok = (r0 < N), v1ok = (r1 < N);
  const float* base0 = &X[(long)r0 * K + kg * 8];
  const float* base1 = &X[(long)r1 * K + kg * 8];

#pragma unroll
  for (int kt = 0; kt < 8; ++kt) {
    bf16x8 a0 = {}, a1 = {};
    if (v0ok) {
      const float* p = base0 + kt * 32;
      float4 u = *(const float4*)p, v = *(const float4*)(p + 4);
      union { uint4 q; bf16x8 b; } cv;
      cv.q.x = pk2(u.x, u.y); cv.q.y = pk2(u.z, u.w);
      cv.q.z = pk2(v.x, v.y); cv.q.w = pk2(v.z, v.w);
      a0 = cv.b;
    }
    if (v1ok) {
      const float* p = base1 + kt * 32;
      float4 u = *(const float4*)p, v = *(const float4*)(p + 4);
      union { uint4 q; bf16x8 b; } cv;
      cv.q.x = pk2(u.x, u.y); cv.q.y = pk2(u.z, u.w);
      cv.q.z = pk2(v.x, v.y); cv.q.w = pk2(v.z, v.w);
      a1 = cv.b;
    }
    int ko = kt * 16 + kg * 4;
#pragma unroll
    for (int f = 0; f < 8; ++f) {
      bf16x8 b = *(const bf16x8*)&Wt[(f * 16 + lr) * 144 + ko];
      acc[0][f] = __builtin_amdgcn_mfma_f32_16x16x32_bf16(a0, b, acc[0][f], 0, 0, 0);
      acc[1][f] = __builtin_amdgcn_mfma_f32_16x16x32_bf16(a1, b, acc[1][f], 0, 0, 0);
    }
  }
  // tail kt=8: kb = 256 + kg*8; only kg==0 in-range (k 256..259, 4 floats)
  {
    bf16x8 a0 = {}, a1 = {};
    if (kg == 0) {
      if (v0ok) {
        float4 u = *(const float4*)&X[(long)r0 * K + 256];
        union { uint4 q; bf16x8 b; } cv;
        cv.q.x = pk2(u.x, u.y); cv.q.y = pk2(u.z, u.w);
        cv.q.z = 0u; cv.q.w = 0u;
        a0 = cv.b;
      }
      if (v1ok) {
        float4 u = *(const float4*)&X[(long)r1 * K + 256];
        union { uint4 q; bf16x8 b; } cv;
        cv.q.x = pk2(u.x, u.y); cv.q.y = pk2(u.z, u.w);
        cv.q.z = 0u; cv.q.w = 0u;
        a1 = cv.b;
      }
    }
    int ko = 128 + kg * 4;
#pragma unroll
    for (int f = 0; f < 8; ++f) {
      bf16x8 b = *(const bf16x8*)&Wt[(f * 16 + lr) * 144 + ko];
      acc[0][f] = __builtin_amdgcn_mfma_f32_16x16x32_bf16(a0, b, acc[0][f], 0, 0, 0);
      acc[1][f] = __builtin_amdgcn_mfma_f32_16x16x32_bf16(a1, b, acc[1][f], 0, 0, 0);
    }
  }
#pragma unroll
  for (int rt = 0; rt < 2; ++rt) {
#pragma unroll
    for (int reg = 0; reg < 4; ++reg) {
      int row = wr0 + rt * 16 + kg * 4 + reg;
      float ds = (row < N) ? dscale[row] : 0.f;
#pragma unroll
      for (int f = 0; f < 8; ++f) {
        float v = acc[rt][f][reg] * ds;
        float pv = __shfl_xor(v, 1);
        if (!(l & 1) && row < N)
          Cu[(long)row * 64 + ((f * 16 + lr) >> 1)] = pk2(v, pv);
      }
    }
  }
}

// ---------------- pull aggregation v4: 16 lanes x uint4 per node ----------------
__global__ __launch_bounds__(256) void k_agg(const uint4* __restrict__ T4,  // [N][16]
                                             const float* __restrict__ dinv,
                                             const int* __restrict__ rowstart,
                                             const int* __restrict__ deg,
                                             const int* __restrict__ csr,
                                             const float* __restrict__ bias,
                                             uint4* __restrict__ outu,      // [N][16]
                                             int N) {
  int t = threadIdx.x;
  int grp = t >> 4;        // node slot 0..15
  int lane = t & 15;       // uint4 slot in row (8 channels)
  int i = blockIdx.x * 16 + grp;
  if (i >= N) return;

  int c0 = lane * 8;
  float b0 = bias[c0 + 0], b1 = bias[c0 + 1], b2 = bias[c0 + 2], b3 = bias[c0 + 3];
  float b4 = bias[c0 + 4], b5 = bias[c0 + 5], b6 = bias[c0 + 6], b7 = bias[c0 + 7];

  uint4 su = T4[(long)i * 16 + lane];  // self-loop (pre-scaled)
  float a0 = blo(su.x), a1 = bhi(su.x), a2 = blo(su.y), a3 = bhi(su.y);
  float a4 = blo(su.z), a5 = bhi(su.z), a6 = blo(su.w), a7 = bhi(su.w);

  int s0 = rowstart[i];
  int d = deg[i];
  int j = 0;
  for (; j + 3 < d; j += 4) {
    int n1 = csr[s0 + j];
    int n2 = csr[s0 + j + 1];
    int n3 = csr[s0 + j + 2];
    int n4 = csr[s0 + j + 3];
    uint4 u1 = T4[(long)n1 * 16 + lane];
    uint4 u2 = T4[(long)n2 * 16 + lane];
    uint4 u3 = T4[(long)n3 * 16 + lane];
    uint4 u4 = T4[(long)n4 * 16 + lane];
    a0 += (blo(u1.x) + blo(u2.x)) + (blo(u3.x) + blo(u4.x));
    a1 += (bhi(u1.x) + bhi(u2.x)) + (bhi(u3.x) + bhi(u4.x));
    a2 += (blo(u1.y) + blo(u2.y)) + (blo(u3.y) + blo(u4.y));
    a3 += (bhi(u1.y) + bhi(u2.y)) + (bhi(u3.y) + bhi(u4.y));
    a4 += (blo(u1.z) + blo(u2.z)) + (blo(u3.z) + blo(u4.z));
    a5 += (bhi(u1.z) + bhi(u2.z)) + (bhi(u3.z) + bhi(u4.z));
    a6 += (blo(u1.w) + blo(u2.w)) + (blo(u3.w) + blo(u4.w));
    a7 += (bhi(u1.w) + bhi(u2.w)) + (bhi(u3.w) + bhi(u4.w));
  }
  for (; j < d; ++j) {
    int n1 = csr[s0 + j];
    uint4 u1 = T4[(long)n1 * 16 + lane];
    a0 += blo(u1.x); a1 += bhi(u1.x); a2 += blo(u1.y); a3 += bhi(u1.y);
    a4 += blo(u1.z); a5 += bhi(u1.z); a6 += blo(u1.w); a7 += bhi(u1.w);
  }
  float di = dinv[i];
  float v0 = fmaxf(di * a0 + b0, 0.f);
  float v1 = fmaxf(di * a1 + b1, 0.f);
  float v2 = fmaxf(di * a2 + b2, 0.f);
  float v3 = fmaxf(di * a3 + b3, 0.f);
  float v4 = fmaxf(di * a4 + b4, 0.f);
  float v5 = fmaxf(di * a5 + b5, 0.f);
  float v6 = fmaxf(di * a6 + b6, 0.f);
  float v7 = fmaxf(di * a7 + b7, 0.f);
  uint4 o;
  o.x = pk2(v0, v1); o.y = pk2(v2, v3); o.z = pk2(v4, v5); o.w = pk2(v6, v7);
  outu[(long)i * 16 + lane] = o;
}

// ---------------- graph start offsets from sorted batch ----------------
__global__ void k_starts(const int* __restrict__ batch, int N, int* __restrict__ start) {
  int i = blockIdx.x * blockDim.x + threadIdx.x;
  int stride = gridDim.x * blockDim.x;
  for (; i < N; i += stride) {
    int g = batch[i];
    if (i == 0) {
      start[g] = 0;
    } else if (batch[i - 1] != g) {
      start[g] = i;
    }
  }
}

// parallel back-fill of empty graphs via reverse min-scan (starts monotone)
__global__ __launch_bounds__(256) void k_fix_starts(int* __restrict__ start, int G, int N) {
  __shared__ int sh[256];
  int t = threadIdx.x;
  int v = (t < G) ? start[t] : N;
  if (v < 0) v = N;
  sh[t] = v;
  __syncthreads();
  for (int off = 1; off < 256; off <<= 1) {
    int x = (t + off < 256) ? sh[t + off] : N;
    int nv = min(sh[t], x);
    __syncthreads();
    sh[t] = nv;
    __syncthreads();
  }
  if (t < G) start[t] = sh[t];
  if (t == 0) start[G] = N;
}

// ---------------- parallel mean-pool (batch sorted, h bf16 [N][64]) -------------
__global__ __launch_bounds__(256) void k_pool2(const unsigned* __restrict__ hu,
                                               const int* __restrict__ batch,
                                               float* __restrict__ psum, int N) {
  int t = threadIdx.x;
  int rg = t >> 6;        // row group 0..3
  int lane = t & 63;      // u32 index in row
  long base = (long)blockIdx.x * 64;
  float a0 = 0.f, a1 = 0.f;
  int cur = -1;
#pragma unroll
  for (int j = 0; j < 16; ++j) {
    long r = base + j * 4 + rg;
    if (r >= N) break;
    int g = batch[r];
    if (g != cur) {
      if (cur >= 0) {
        atomicAdd(&psum[cur * HID + lane * 2], a0);
        atomicAdd(&psum[cur * HID + lane * 2 + 1], a1);
        a0 = 0.f; a1 = 0.f;
      }
      cur = g;
    }
    unsigned u = hu[r * 64 + lane];
    a0 += blo(u); a1 += bhi(u);
  }
  if (cur >= 0) {
    atomicAdd(&psum[cur * HID + lane * 2], a0);
    atomicAdd(&psum[cur * HID + lane * 2 + 1], a1);
  }
}

// ---------------- MLP head ----------------
__global__ __launch_bounds__(128) void k_head(const float* __restrict__ psum,
                                              const int* __restrict__ gstart,
                                              const float* __restrict__ fc1w,
                                              const float* __restrict__ fc1b,
                                              const float* __restrict__ fc2w,
                                              const float* __restrict__ fc2b,
                                              float* __restrict__ out, int G) {
  __shared__ float pooled[HID];
  __shared__ float z1[HID];
  int g = blockIdx.x;
  int c = threadIdx.x;
  float cn = fmaxf((float)(gstart[g + 1] - gstart[g]), 1.f);
  pooled[c] = psum[g * HID + c] / cn;
  __syncthreads();
  float a = fc1b[c];
#pragma unroll 8
  for (int k = 0; k < HID; ++k) a += pooled[k] * fc1w[k * HID + c];
  z1[c] = fmaxf(a, 0.f);
  __syncthreads();
  if (c < 16) {
    float o = fc2b[c];
#pragma unroll 8
    for (int k = 0; k < HID; ++k) o += z1[k] * fc2w[k * 16 + c];
    out[g * 16 + c] = o;
  }
}

extern "C" void kernel_launch(void* const* d_in, const int* in_sizes, int n_in,
                              void* d_out, int out_size, void* d_ws, size_t ws_size,
                              hipStream_t stream) {
  const float* x     = (const float*)d_in[0];
  const int*   ei    = (const int*)d_in[1];
  const int*   batch = (const int*)d_in[2];
  const float* w1    = (const float*)d_in[3];
  const float* b1    = (const float*)d_in[4];
  const float* w2    = (const float*)d_in[5];
  const float* b2    = (const float*)d_in[6];
  const float* w3    = (const float*)d_in[7];
  const float* b3    = (const float*)d_in[8];
  const float* fc1w  = (const float*)d_in[9];
  const float* fc1b  = (const float*)d_in[10];
  const float* fc2w  = (const float*)d_in[11];
  const float* fc2b  = (const float*)d_in[12];
  float* out = (float*)d_out;

  const int IN = in_sizes[3] / HID;   // 260
  const int N  = in_sizes[0] / IN;    // 100000
  const int E  = in_sizes[1] / 2;     // 3200000
  const int G  = out_size / 16;       // 64

  const int* srcp = ei;
  const int* dstp = ei + E;

  // ---- workspace carve ----
  char* wsp = (char*)d_ws;
  auto alloc = [&](size_t bytes) {
    char* p = wsp;
    wsp += (bytes + 255) & ~(size_t)255;
    return p;
  };
  int*   deg      = (int*)alloc((size_t)N * 4);
  int*   rowstart = (int*)alloc((size_t)N * 4);
  int*   bhist    = (int*)alloc(NB * 4);
  int*   bstart   = (int*)alloc((NB + 1) * 4);
  int*   gcur     = (int*)alloc(NB * 4);
  int*   gstart   = (int*)alloc((size_t)(G + 1) * 4);
  float* dinv     = (float*)alloc((size_t)N * 4);
  float* psum     = (float*)alloc((size_t)G * HID * 4);
  unsigned* Wt1   = (unsigned*)alloc(128 * 144 * 4);
  unsigned* Wt2   = (unsigned*)alloc(128 * 64 * 4);
  unsigned* Wt3   = (unsigned*)alloc(128 * 64 * 4);
  int*   csr      = (int*)alloc((size_t)E * 4);
  unsigned* bufA  = (unsigned*)alloc((size_t)N * 64 * 4);  // bf16 [N][128] packed
  unsigned* bufB  = (unsigned*)alloc((size_t)N * 64 * 4);  // bf16 [N][128] packed
  // binned edge array (E x 4B = 12.8MB) aliases bufA; consumed before first GEMM.
  unsigned* binned = (unsigned*)bufA;

  // ---- fused prep (weights + init) ----
  k_prep_init<<<136, 256, 0, stream>>>(w1, w2, w3, Wt1, Wt2, Wt3,
                                       psum, gstart, bhist, IN, G);

  // ---- binned CSR build (u32-packed, fused build) ----
  k_hist<<<512, 256, 0, stream>>>(dstp, E, N, bhist);
  k_bscan<<<1, NB, 0, stream>>>(bhist, bstart, gcur, E);
  k_scatter<<<782, 256, 0, stream>>>(srcp, dstp, E, N, binned, gcur);
  k_build<<<NB, 256, 0, stream>>>(binned, bstart, N, deg, dinv, rowstart, csr);

  // ---- graph boundaries ----
  k_starts<<<256, 256, 0, stream>>>(batch, N, gstart);
  k_fix_starts<<<1, 256, 0, stream>>>(gstart, G, N);

  // ---- 3 GCN layers: MFMA GEMM (epilogue scales by dinv, packs bf16) + agg ----
  int gblocks = (N + 127) / 128;
  int ablocks = (N + 15) / 16;
  k_gemm1_mf<<<gblocks, 256, 0, stream>>>(x, Wt1, dinv, bufA, N);
  k_agg<<<ablocks, 256, 0, stream>>>((const uint4*)bufA, dinv, rowstart, deg, csr, b1,
                                     (uint4*)bufB, N);

  k_gemm_mf<<<gblocks, 256, 0, stream>>>(bufB, Wt2, dinv, bufA, N);
  k_agg<<<ablocks, 256, 0, stream>>>((const uint4*)bufA, dinv, rowstart, deg, csr, b2,
                                     (uint4*)bufB, N);

  k_gemm_mf<<<gblocks, 256, 0, stream>>>(bufB, Wt3, dinv, bufA, N);
  k_agg<<<ablocks, 256, 0, stream>>>((const uint4*)bufA, dinv, rowstart, deg, csr, b3,
                                     (uint4*)bufB, N);

  // ---- pool + head ----
  int pblocks = (N + 63) / 64;
  k_pool2<<<pblocks, 256, 0, stream>>>(bufB, batch, psum, N);
  k_head<<<G, 128, 0, stream>>>(psum, gstart, fc1w, fc1b, fc2w, fc2b, out, G);
}